// Round 1
// baseline (25857.309 us; speedup 1.0000x reference)
//
#include <hip/hip_runtime.h>

#define EPS_BN 1e-5f
constexpr int PP = 16384;   // 128*128 pixels at fusion resolution

// ---------------- BN param prep: scale = g/sqrt(v+eps), shift = b - m*scale ----
// sets: 0 = bn2, 1..4 = convs0..3, 5 = emb
__global__ void bn_prep_k(const float* __restrict__ g0, const float* __restrict__ b0,
                          const float* __restrict__ m0, const float* __restrict__ v0,
                          const float* __restrict__ cg, const float* __restrict__ cb,
                          const float* __restrict__ cm, const float* __restrict__ cv,
                          const float* __restrict__ eg, const float* __restrict__ eb,
                          const float* __restrict__ em, const float* __restrict__ ev,
                          float* __restrict__ scale, float* __restrict__ shift) {
  int c = threadIdx.x;
  float s = g0[c] * rsqrtf(v0[c] + EPS_BN);
  scale[c] = s; shift[c] = b0[c] - m0[c] * s;
#pragma unroll
  for (int i = 0; i < 4; ++i) {
    float si = cg[i*256+c] * rsqrtf(cv[i*256+c] + EPS_BN);
    scale[(1+i)*256+c] = si; shift[(1+i)*256+c] = cb[i*256+c] - cm[i*256+c]*si;
  }
  float se = eg[c] * rsqrtf(ev[c] + EPS_BN);
  scale[5*256+c] = se; shift[5*256+c] = eb[c] - em[c]*se;
}

// ---------------- weight transpose: W[O][256][KK] -> Wt[(k*256+c)][NS], zero-pad o>=O
__global__ void transpose_w_k(const float* __restrict__ Wsrc, float* __restrict__ Wt,
                              int Ocnt, int KK, int NS) {
  int idx = blockIdx.x * 256 + threadIdx.x;
  int total = KK * 256 * NS;
  if (idx >= total) return;
  int ck = idx / NS, o = idx - ck * NS;
  int k = ck >> 8, c = ck & 255;
  Wt[idx] = (o < Ocnt) ? Wsrc[(o * 256 + c) * KK + k] : 0.f;
}

// ---------------- resize bilinear (align_corners=True), NCHW in -> NHWC out [16384][256]
__global__ void resize_k(const float* __restrict__ in, float* __restrict__ out, int Hs) {
  int tid = blockIdx.x * 256 + threadIdx.x;
  int p = tid >> 8, c = tid & 255;
  int oy = p >> 7, ox = p & 127;
  float sc = (float)(Hs - 1) / 127.0f;
  float ys = oy * sc, xs = ox * sc;
  int y0 = (int)ys; if (y0 > Hs - 2) y0 = Hs - 2;
  int x0 = (int)xs; if (x0 > Hs - 2) x0 = Hs - 2;
  float wy = ys - (float)y0, wx = xs - (float)x0;
  const float* pl = in + c * Hs * Hs;
  float v00 = pl[y0*Hs + x0],     v01 = pl[y0*Hs + x0 + 1];
  float v10 = pl[(y0+1)*Hs + x0], v11 = pl[(y0+1)*Hs + x0 + 1];
  out[tid] = (v00*(1.f-wx) + v01*wx)*(1.f-wy) + (v10*(1.f-wx) + v11*wx)*wy;
}

// ---------------- implicit GEMM  out[p, oc] = sum_ck A[p, ck] * Wt[ck, oc]
// MODE 0: conv3x3 NHWC (zero pad=1), ck = k*256+c, k=(dy,dx)
// MODE 1: deform conv (DCNv1 bilinear sampling via offs[p][18])
// MODE 2: 1x1 conv, ck = c, K=256
// EPI bits: 1=bias, 2=bn+relu, 4=accumulate, 8=NCHW output
template<int MODE, int BM, int BN, int TM, int TN, int EPI>
__launch_bounds__(256)
__global__ void gemm_k(const float* __restrict__ Asrc, const float* __restrict__ offs,
                       const float* __restrict__ Wt, float* __restrict__ out,
                       const float* __restrict__ bias,
                       const float* __restrict__ scale, const float* __restrict__ shift,
                       int K, int NS, int OutN, int outStride) {
  constexpr int BK = 16;
  constexpr int PADA = 4, PADB = 4;
  __shared__ float sA[BK][BM + PADA];
  __shared__ float sB[BK][BN + PADB];
  const int p0  = blockIdx.x * BM;
  const int oc0 = blockIdx.y * BN;
  const int t = threadIdx.x;
  constexpr int MG = BM / TM;                 // m-groups
  const int m0 = (t % MG) * TM;
  const int n0 = (t / MG) * TN;

  float acc[TM][TN];
#pragma unroll
  for (int i = 0; i < TM; ++i)
#pragma unroll
    for (int j = 0; j < TN; ++j) acc[i][j] = 0.f;

  const int KC = K / BK;
  for (int ckb = 0; ckb < KC; ++ckb) {
    // ---- load B chunk [BK][BN]
    for (int i = t; i < BK * BN; i += 256) {
      int ci = i / BN, ocl = i - ci * BN;
      sB[ci][ocl] = Wt[(ckb * BK + ci) * NS + oc0 + ocl];
    }
    // ---- load A chunk [BK][BM]
    if (MODE == 2) {
      int c0 = ckb * BK;
      for (int i = t; i < BK * BM; i += 256) {
        int ci = i & (BK - 1), pl = i / BK;
        sA[ci][pl] = Asrc[(p0 + pl) * 256 + c0 + ci];
      }
    } else if (MODE == 0) {
      int k = ckb / (256 / BK), c0 = (ckb % (256 / BK)) * BK;
      int dy = k / 3 - 1, dx = k % 3 - 1;
      for (int i = t; i < BK * BM; i += 256) {
        int ci = i & (BK - 1), pl = i / BK;
        int p = p0 + pl, y = p >> 7, x = p & 127;
        int yy = y + dy, xx = x + dx;
        float v = 0.f;
        if ((unsigned)yy < 128u && (unsigned)xx < 128u)
          v = Asrc[(((yy << 7) + xx) << 8) + c0 + ci];
        sA[ci][pl] = v;
      }
    } else { // MODE 1: deform
      int k = ckb / (256 / BK), c0 = (ckb % (256 / BK)) * BK;
      float ky = (float)(k / 3 - 1), kx = (float)(k % 3 - 1);
      for (int i = t; i < BK * BM; i += 256) {
        int ci = i & (BK - 1), pl = i / BK;
        int p = p0 + pl, y = p >> 7, x = p & 127;
        float2 o2 = *reinterpret_cast<const float2*>(offs + p * 18 + 2 * k);
        float yy = (float)y + ky + o2.x;
        float xx = (float)x + kx + o2.y;
        float y0f = floorf(yy), x0f = floorf(xx);
        float wy = yy - y0f, wx = xx - x0f;
        int y0 = (int)y0f, x0 = (int)x0f;
        float w00 = (1.f - wy) * (1.f - wx), w01 = (1.f - wy) * wx;
        float w10 = wy * (1.f - wx),         w11 = wy * wx;
        const float* base = Asrc + c0 + ci;
        float v = 0.f;
        if ((unsigned)y0 < 128u) {
          int rb = (y0 << 7);
          if ((unsigned)x0 < 128u)       v += w00 * base[(rb + x0) << 8];
          if ((unsigned)(x0 + 1) < 128u) v += w01 * base[(rb + x0 + 1) << 8];
        }
        if ((unsigned)(y0 + 1) < 128u) {
          int rb = ((y0 + 1) << 7);
          if ((unsigned)x0 < 128u)       v += w10 * base[(rb + x0) << 8];
          if ((unsigned)(x0 + 1) < 128u) v += w11 * base[(rb + x0 + 1) << 8];
        }
        sA[ci][pl] = v;
      }
    }
    __syncthreads();
    // ---- FMA micro-kernel
#pragma unroll
    for (int kk = 0; kk < BK; ++kk) {
      float a[TM], b[TN];
#pragma unroll
      for (int i = 0; i < TM; ++i) a[i] = sA[kk][m0 + i];
#pragma unroll
      for (int j = 0; j < TN; ++j) b[j] = sB[kk][n0 + j];
#pragma unroll
      for (int i = 0; i < TM; ++i)
#pragma unroll
        for (int j = 0; j < TN; ++j) acc[i][j] += a[i] * b[j];
    }
    __syncthreads();
  }

  // ---- epilogue
#pragma unroll
  for (int j = 0; j < TN; ++j) {
    int oc = oc0 + n0 + j;
    if (oc >= OutN) continue;
    float bs = (EPI & 1) ? bias[oc] : 0.f;
    float sc = (EPI & 2) ? scale[oc] : 1.f;
    float sh = (EPI & 2) ? shift[oc] : 0.f;
#pragma unroll
    for (int i = 0; i < TM; ++i) {
      int p = p0 + m0 + i;
      float v = acc[i][j] + bs;
      if (EPI & 2) v = fmaxf(v * sc + sh, 0.f);
      long idx = (EPI & 8) ? ((long)oc * PP + p) : ((long)p * outStride + oc);
      if (EPI & 4) out[idx] += v; else out[idx] = v;
    }
  }
}

extern "C" void kernel_launch(void* const* d_in, const int* in_sizes, int n_in,
                              void* d_out, int out_size, void* d_ws, size_t ws_size,
                              hipStream_t stream) {
  const float* feats[5];
  for (int i = 0; i < 5; ++i) feats[i] = (const float*)d_in[i];
  int fsz[5] = {256, 128, 64, 32, 16};
  const float* off1_w = (const float*)d_in[5];
  const float* off1_b = (const float*)d_in[6];
  const float* dc1_w  = (const float*)d_in[7];
  const float* off2_w = (const float*)d_in[8];
  const float* off2_b = (const float*)d_in[9];
  const float* dc2_w  = (const float*)d_in[10];
  const float* bn2_g  = (const float*)d_in[11];
  const float* bn2_b  = (const float*)d_in[12];
  const float* bn2_m  = (const float*)d_in[13];
  const float* bn2_v  = (const float*)d_in[14];
  const float* convs_w = (const float*)d_in[15];
  const float* convs_g = (const float*)d_in[16];
  const float* convs_b = (const float*)d_in[17];
  const float* convs_m = (const float*)d_in[18];
  const float* convs_v = (const float*)d_in[19];
  const float* emb_w  = (const float*)d_in[20];
  const float* emb_g  = (const float*)d_in[21];
  const float* emb_b  = (const float*)d_in[22];
  const float* emb_m  = (const float*)d_in[23];
  const float* emb_v  = (const float*)d_in[24];
  const float* logit_w = (const float*)d_in[25];
  const float* logit_b = (const float*)d_in[26];

  float* ws = (float*)d_ws;
  float* X  = ws;                       // 16384*256
  float* R  = X + PP * 256;             // 16384*256
  float* H1 = R + PP * 256;             // 16384*256
  float* O  = H1 + PP * 256;            // 16384*18
  float* Wt_off1 = O + PP * 18;         // 2304*32
  float* Wt_off2 = Wt_off1 + 2304 * 32;
  float* Wt_dc1  = Wt_off2 + 2304 * 32; // 2304*256
  float* Wt_dc2  = Wt_dc1 + 2304 * 256;
  float* Wt_c    = Wt_dc2 + 2304 * 256; // 4 * 2304*256
  float* Wt_logit = Wt_c + 4 * 2304 * 256; // 256*256
  float* Wt_emb   = Wt_logit + 256 * 256;
  float* bnscale  = Wt_emb + 256 * 256; // 6*256
  float* bnshift  = bnscale + 6 * 256;

  bn_prep_k<<<1, 256, 0, stream>>>(bn2_g, bn2_b, bn2_m, bn2_v,
                                   convs_g, convs_b, convs_m, convs_v,
                                   emb_g, emb_b, emb_m, emb_v, bnscale, bnshift);

  auto tw = [&](const float* src, float* dst, int Ocnt, int KK, int NS) {
    int total = KK * 256 * NS;
    transpose_w_k<<<(total + 255) / 256, 256, 0, stream>>>(src, dst, Ocnt, KK, NS);
  };
  tw(off1_w, Wt_off1, 18, 9, 32);
  tw(off2_w, Wt_off2, 18, 9, 32);
  tw(dc1_w,  Wt_dc1, 256, 9, 256);
  tw(dc2_w,  Wt_dc2, 256, 9, 256);
  for (int i = 0; i < 4; ++i) tw(convs_w + i * 2304 * 256, Wt_c + i * 2304 * 256, 256, 9, 256);
  tw(emb_w,   Wt_emb,  256, 1, 256);
  tw(logit_w, Wt_logit, 183, 1, 256);

  const dim3 big(PP / 128, 2), blk(256);
  const dim3 sml(PP / 256, 1);
  int order[5] = {1, 0, 2, 3, 4};
  for (int li = 0; li < 5; ++li) {
    int l = order[li];
    resize_k<<<PP, 256, 0, stream>>>(feats[l], R, fsz[l]);
    gemm_k<0, 256, 32, 8, 4, 1><<<sml, blk, 0, stream>>>(R, nullptr, Wt_off1, O, off1_b,
                                                         nullptr, nullptr, 2304, 32, 18, 18);
    gemm_k<1, 128, 128, 8, 8, 0><<<big, blk, 0, stream>>>(R, O, Wt_dc1, H1, nullptr,
                                                          nullptr, nullptr, 2304, 256, 256, 256);
    gemm_k<0, 256, 32, 8, 4, 1><<<sml, blk, 0, stream>>>(H1, nullptr, Wt_off2, O, off2_b,
                                                         nullptr, nullptr, 2304, 32, 18, 18);
    if (li == 0)
      gemm_k<1, 128, 128, 8, 8, 2><<<big, blk, 0, stream>>>(H1, O, Wt_dc2, X, nullptr,
                                                            bnscale, bnshift, 2304, 256, 256, 256);
    else
      gemm_k<1, 128, 128, 8, 8, 6><<<big, blk, 0, stream>>>(H1, O, Wt_dc2, X, nullptr,
                                                            bnscale, bnshift, 2304, 256, 256, 256);
  }

  // conv stack: X -> H1 -> R -> H1 -> R
  float* bufs[2] = {H1, R};
  const float* cur = X;
  for (int i = 0; i < 4; ++i) {
    gemm_k<0, 128, 128, 8, 8, 2><<<big, blk, 0, stream>>>(cur, nullptr, Wt_c + i * 2304 * 256,
                                                          bufs[i & 1], nullptr,
                                                          bnscale + (1 + i) * 256, bnshift + (1 + i) * 256,
                                                          2304, 256, 256, 256);
    cur = bufs[i & 1];
  }

  float* outp = (float*)d_out;
  gemm_k<2, 128, 128, 8, 8, 9><<<big, blk, 0, stream>>>(cur, nullptr, Wt_logit, outp, logit_b,
                                                        nullptr, nullptr, 256, 256, 183, 0);
  gemm_k<2, 128, 128, 8, 8, 10><<<big, blk, 0, stream>>>(cur, nullptr, Wt_emb, outp + 183 * PP,
                                                         nullptr, bnscale + 5 * 256, bnshift + 5 * 256,
                                                         256, 256, 256, 0);
}

// Round 2
// 1541.912 us; speedup vs baseline: 16.7696x; 16.7696x over previous
//
#include <hip/hip_runtime.h>
#include <stdint.h>

#define EPS_BN 1e-5f
constexpr int PP = 16384;   // 128*128 pixels at fusion resolution
using short8 = __attribute__((ext_vector_type(8))) short;
using f32x4  = __attribute__((ext_vector_type(4))) float;

__device__ inline float bf2f(unsigned short u) {
  unsigned v = ((unsigned)u) << 16; float f; __builtin_memcpy(&f, &v, 4); return f;
}
__device__ inline unsigned short f2bf(float f) {
  unsigned b; __builtin_memcpy(&b, &f, 4);
  b += 0x7FFFu + ((b >> 16) & 1u);
  return (unsigned short)(b >> 16);
}

#define GLD16(g, l) __builtin_amdgcn_global_load_lds( \
    (__attribute__((address_space(1))) void*)(void*)(g), \
    (__attribute__((address_space(3))) void*)(void*)(l), 16, 0, 0)

// ---------------- BN param prep ----------------
__global__ void bn_prep_k(const float* __restrict__ g0, const float* __restrict__ b0,
                          const float* __restrict__ m0, const float* __restrict__ v0,
                          const float* __restrict__ cg, const float* __restrict__ cb,
                          const float* __restrict__ cm, const float* __restrict__ cv,
                          const float* __restrict__ eg, const float* __restrict__ eb,
                          const float* __restrict__ em, const float* __restrict__ ev,
                          float* __restrict__ scale, float* __restrict__ shift) {
  int c = threadIdx.x;
  float s = g0[c] * rsqrtf(v0[c] + EPS_BN);
  scale[c] = s; shift[c] = b0[c] - m0[c] * s;
#pragma unroll
  for (int i = 0; i < 4; ++i) {
    float si = cg[i*256+c] * rsqrtf(cv[i*256+c] + EPS_BN);
    scale[(1+i)*256+c] = si; shift[(1+i)*256+c] = cb[i*256+c] - cm[i*256+c]*si;
  }
  float se = eg[c] * rsqrtf(ev[c] + EPS_BN);
  scale[5*256+c] = se; shift[5*256+c] = eb[c] - em[c]*se;
}

// ---------------- weight prep: w[O][256][KK] fp32 -> W2[o][k*256+c] bf16, pad o>=Ocnt
__global__ void prep_w_k(const float* __restrict__ w, unsigned short* __restrict__ W2,
                         int Ocnt, int KK, int NPAD) {
  int idx = blockIdx.x * 256 + threadIdx.x;
  int total = NPAD * KK * 256;
  if (idx >= total) return;
  int o = idx / (KK * 256); int rem = idx - o * (KK * 256);
  int kpt = rem >> 8, c = rem & 255;
  W2[idx] = (o < Ocnt) ? f2bf(w[(o * 256 + c) * KK + kpt]) : (unsigned short)0;
}

// ---------------- resize bilinear (align_corners) NCHW fp32 -> NHWC bf16 [16384][256]
__global__ void resize_k(const float* __restrict__ in, unsigned short* __restrict__ out, int Hs) {
  int tid = blockIdx.x * 256 + threadIdx.x;
  int p = tid >> 8, c = tid & 255;
  int oy = p >> 7, ox = p & 127;
  float sc = (float)(Hs - 1) / 127.0f;
  float ys = oy * sc, xs = ox * sc;
  int y0 = (int)ys; if (y0 > Hs - 2) y0 = Hs - 2;
  int x0 = (int)xs; if (x0 > Hs - 2) x0 = Hs - 2;
  float wy = ys - (float)y0, wx = xs - (float)x0;
  const float* pl = in + (size_t)c * Hs * Hs;
  float v00 = pl[y0*Hs + x0],     v01 = pl[y0*Hs + x0 + 1];
  float v10 = pl[(y0+1)*Hs + x0], v11 = pl[(y0+1)*Hs + x0 + 1];
  out[tid] = f2bf((v00*(1.f-wx) + v01*wx)*(1.f-wy) + (v10*(1.f-wx) + v11*wx)*wy);
}

// ---------------- deform sampler: in bf16 NHWC [PP][256], off fp32 [PP][32] -> S bf16 [PP][2304]
__global__ void sample_k(const unsigned short* __restrict__ in, const float* __restrict__ off,
                         unsigned short* __restrict__ S) {
  int k  = blockIdx.y;
  int pp = blockIdx.x * 8 + (threadIdx.x >> 5);
  int q  = threadIdx.x & 31;
  float dy = off[pp * 32 + 2 * k], dx = off[pp * 32 + 2 * k + 1];
  int y = pp >> 7, x = pp & 127;
  float yy = (float)(y + k / 3 - 1) + dy;
  float xx = (float)(x + k % 3 - 1) + dx;
  float y0f = floorf(yy), x0f = floorf(xx);
  float wy = yy - y0f, wx = xx - x0f;
  int y0 = (int)y0f, x0 = (int)x0f;
  float w00 = (1.f-wy)*(1.f-wx), w01 = (1.f-wy)*wx, w10 = wy*(1.f-wx), w11 = wy*wx;
  float o[8] = {0,0,0,0,0,0,0,0};
  auto corner = [&](int yi, int xi, float wgt) {
    if ((unsigned)yi < 128u && (unsigned)xi < 128u) {
      short8 v = *(const short8*)(in + (size_t)(((yi << 7) + xi)) * 256 + q * 8);
#pragma unroll
      for (int j = 0; j < 8; ++j) o[j] += wgt * bf2f((unsigned short)v[j]);
    }
  };
  corner(y0, x0, w00); corner(y0, x0 + 1, w01);
  corner(y0 + 1, x0, w10); corner(y0 + 1, x0 + 1, w11);
  unsigned short r[8];
#pragma unroll
  for (int j = 0; j < 8; ++j) r[j] = f2bf(o[j]);
  *(short8*)(S + (size_t)pp * 2304 + k * 256 + q * 8) = *(short8*)r;
}

// ---------------- MFMA GEMM: C[p,oc] partial = sum_k A[p,k] * B[oc,k]
// CONV3=0: A dense [M][Ktot] bf16.  CONV3=1: A = NHWC bf16 [PP][256], im2col 3x3 pad=1 on the fly.
// B: [NStot][Ktot] bf16 (row = output channel). partial: [KS][PP][NStot] fp32.
template<int CONV3>
__global__ void mm_k(const unsigned short* __restrict__ A, const unsigned short* __restrict__ B,
                     float* __restrict__ partial, const unsigned short* __restrict__ zbuf,
                     int Ktot, int ksteps, int NStot) {
  __shared__ unsigned short sA[4096];   // [128][32] bf16
  __shared__ unsigned short sB[4096];   // [128][32] bf16
  const int t = threadIdx.x;
  const int w = t >> 6, l = t & 63;
  const int p0 = blockIdx.x * 128, n0 = blockIdx.y * 128;
  const int k_base = blockIdx.z * ksteps * 32;
  const int lr = l & 15, lq = l >> 4;
  const int wm = w >> 1, wn = w & 1;
  char* sAb = (char*)sA; char* sBb = (char*)sB;

  f32x4 acc[4][4];
#pragma unroll
  for (int m = 0; m < 4; ++m)
#pragma unroll
    for (int n = 0; n < 4; ++n) acc[m][n] = (f32x4){0.f, 0.f, 0.f, 0.f};

  for (int ks = 0; ks < ksteps; ++ks) {
    int k0 = k_base + ks * 32;
    // stage B (8KB): chunks t and t+256; chunk -> row=ch>>2, col8=(ch&3)
    {
      int ch = t;
      GLD16(B + (size_t)(n0 + (ch >> 2)) * Ktot + k0 + (ch & 3) * 8, sBb + w * 1024);
      ch = t + 256;
      GLD16(B + (size_t)(n0 + (ch >> 2)) * Ktot + k0 + (ch & 3) * 8, sBb + 4096 + w * 1024);
    }
    // stage A (8KB)
    if (CONV3) {
      int kpt = k0 >> 8, c0 = k0 & 255;
      int dy = kpt / 3 - 1, dx = kpt % 3 - 1;
      int ch = t;
      {
        int r = p0 + (ch >> 2); int yy = (r >> 7) + dy, xx = (r & 127) + dx;
        const unsigned short* src = ((unsigned)yy < 128u && (unsigned)xx < 128u)
            ? A + (size_t)((yy << 7) + xx) * 256 + c0 + (ch & 3) * 8 : zbuf;
        GLD16(src, sAb + w * 1024);
      }
      ch = t + 256;
      {
        int r = p0 + (ch >> 2); int yy = (r >> 7) + dy, xx = (r & 127) + dx;
        const unsigned short* src = ((unsigned)yy < 128u && (unsigned)xx < 128u)
            ? A + (size_t)((yy << 7) + xx) * 256 + c0 + (ch & 3) * 8 : zbuf;
        GLD16(src, sAb + 4096 + w * 1024);
      }
    } else {
      int ch = t;
      GLD16(A + (size_t)(p0 + (ch >> 2)) * Ktot + k0 + (ch & 3) * 8, sAb + w * 1024);
      ch = t + 256;
      GLD16(A + (size_t)(p0 + (ch >> 2)) * Ktot + k0 + (ch & 3) * 8, sAb + 4096 + w * 1024);
    }
    __syncthreads();
    short8 af[4], bfr[4];
#pragma unroll
    for (int m = 0; m < 4; ++m)
      af[m] = *(const short8*)(sAb + ((wm * 64 + m * 16 + lr) << 6) + (lq << 4));
#pragma unroll
    for (int n = 0; n < 4; ++n)
      bfr[n] = *(const short8*)(sBb + ((wn * 64 + n * 16 + lr) << 6) + (lq << 4));
#pragma unroll
    for (int m = 0; m < 4; ++m)
#pragma unroll
      for (int n = 0; n < 4; ++n)
        acc[m][n] = __builtin_amdgcn_mfma_f32_16x16x32_bf16(af[m], bfr[n], acc[m][n], 0, 0, 0);
    __syncthreads();
  }

  float* P = partial + ((size_t)blockIdx.z * PP + p0) * NStot + n0;
#pragma unroll
  for (int m = 0; m < 4; ++m)
#pragma unroll
    for (int n = 0; n < 4; ++n)
#pragma unroll
      for (int r = 0; r < 4; ++r) {
        int row = wm * 64 + m * 16 + lq * 4 + r;
        int col = wn * 64 + n * 16 + lr;
        P[(size_t)row * NStot + col] = acc[m][n][r];
      }
}

// ---------------- reduce partials + epilogue
// EPI 0: offsets fp32 [p][32] (+bias oc<18)   1: bf16 plain   2: bf16 bn+relu
// EPI 3: X fp32 += bn+relu   4: X fp32 = bn+relu   5: logit NCHW fp32 (+bias, oc<183)
// EPI 6: emb NCHW fp32 bn+relu
template<int EPI>
__global__ void red_k(const float* __restrict__ partial, int KS, int NStot, int NOUT,
                      float* __restrict__ oF, unsigned short* __restrict__ oB,
                      const float* __restrict__ bias,
                      const float* __restrict__ scale, const float* __restrict__ shift) {
  long e = ((long)blockIdx.x * 256 + threadIdx.x) * 4;
  if (e >= (long)PP * NOUT) return;
  int p = (int)(e / NOUT);
  int oc0 = (int)(e - (long)p * NOUT);
  float4 v = {0.f, 0.f, 0.f, 0.f};
  for (int s = 0; s < KS; ++s) {
    float4 tv = *(const float4*)(partial + ((size_t)s * PP + p) * NStot + oc0);
    v.x += tv.x; v.y += tv.y; v.z += tv.z; v.w += tv.w;
  }
  float vv[4] = {v.x, v.y, v.z, v.w};
#pragma unroll
  for (int j = 0; j < 4; ++j) {
    int oc = oc0 + j; float r = vv[j];
    if (EPI == 0) { if (oc < 18) r += bias[oc]; oF[(size_t)p * 32 + oc] = r; }
    if (EPI == 1) { oB[(size_t)p * 256 + oc] = f2bf(r); }
    if (EPI == 2) { r = fmaxf(r * scale[oc] + shift[oc], 0.f); oB[(size_t)p * 256 + oc] = f2bf(r); }
    if (EPI == 3) { r = fmaxf(r * scale[oc] + shift[oc], 0.f); oF[(size_t)p * 256 + oc] += r; }
    if (EPI == 4) { r = fmaxf(r * scale[oc] + shift[oc], 0.f); oF[(size_t)p * 256 + oc] = r; }
    if (EPI == 5) { if (oc < 183) oF[(size_t)oc * PP + p] = r + bias[oc]; }
    if (EPI == 6) { r = fmaxf(r * scale[oc] + shift[oc], 0.f); oF[(size_t)oc * PP + p] = r; }
  }
}

__global__ void f2b_k(const float* __restrict__ in, unsigned short* __restrict__ out) {
  int i = (blockIdx.x * 256 + threadIdx.x) * 4;
  float4 v = *(const float4*)(in + i);
  unsigned short r[4] = {f2bf(v.x), f2bf(v.y), f2bf(v.z), f2bf(v.w)};
  *(uint2*)(out + i) = *(uint2*)r;
}

extern "C" void kernel_launch(void* const* d_in, const int* in_sizes, int n_in,
                              void* d_out, int out_size, void* d_ws, size_t ws_size,
                              hipStream_t stream) {
  const float* feats[5];
  for (int i = 0; i < 5; ++i) feats[i] = (const float*)d_in[i];
  int fsz[5] = {256, 128, 64, 32, 16};
  const float* off1_w = (const float*)d_in[5];
  const float* off1_b = (const float*)d_in[6];
  const float* dc1_w  = (const float*)d_in[7];
  const float* off2_w = (const float*)d_in[8];
  const float* off2_b = (const float*)d_in[9];
  const float* dc2_w  = (const float*)d_in[10];
  const float* bn2_g  = (const float*)d_in[11];
  const float* bn2_b  = (const float*)d_in[12];
  const float* bn2_m  = (const float*)d_in[13];
  const float* bn2_v  = (const float*)d_in[14];
  const float* convs_w = (const float*)d_in[15];
  const float* convs_g = (const float*)d_in[16];
  const float* convs_b = (const float*)d_in[17];
  const float* convs_m = (const float*)d_in[18];
  const float* convs_v = (const float*)d_in[19];
  const float* emb_w  = (const float*)d_in[20];
  const float* emb_g  = (const float*)d_in[21];
  const float* emb_b  = (const float*)d_in[22];
  const float* emb_m  = (const float*)d_in[23];
  const float* emb_v  = (const float*)d_in[24];
  const float* logit_w = (const float*)d_in[25];
  const float* logit_b = (const float*)d_in[26];

  char* ws = (char*)d_ws;
  size_t off = 0;
  auto alloc = [&](size_t bytes) { char* p = ws + off; off += (bytes + 255) & ~255ull; return p; };
  float* bnscale = (float*)alloc(6 * 256 * 4);
  float* bnshift = (float*)alloc(6 * 256 * 4);
  unsigned short* zbuf = (unsigned short*)alloc(256);
  unsigned short* W2_off1 = (unsigned short*)alloc((size_t)128 * 2304 * 2);
  unsigned short* W2_off2 = (unsigned short*)alloc((size_t)128 * 2304 * 2);
  unsigned short* W2_dc1  = (unsigned short*)alloc((size_t)256 * 2304 * 2);
  unsigned short* W2_dc2  = (unsigned short*)alloc((size_t)256 * 2304 * 2);
  unsigned short* W2_c    = (unsigned short*)alloc((size_t)4 * 256 * 2304 * 2);
  unsigned short* W2_logit = (unsigned short*)alloc((size_t)256 * 256 * 2);
  unsigned short* W2_emb   = (unsigned short*)alloc((size_t)256 * 256 * 2);
  unsigned short* Rb  = (unsigned short*)alloc((size_t)PP * 256 * 2);
  unsigned short* H   = (unsigned short*)alloc((size_t)PP * 256 * 2);
  unsigned short* Xb  = (unsigned short*)alloc((size_t)PP * 256 * 2);
  unsigned short* buf0 = (unsigned short*)alloc((size_t)PP * 256 * 2);
  unsigned short* buf1 = (unsigned short*)alloc((size_t)PP * 256 * 2);
  float* O = (float*)alloc((size_t)PP * 32 * 4);
  float* X = (float*)alloc((size_t)PP * 256 * 4);
  unsigned short* S = (unsigned short*)alloc((size_t)PP * 2304 * 2);
  size_t avail = (ws_size > off) ? (ws_size - off) : 0;
  int KS_MAIN, KS_OFF;
  if (avail >= (size_t)4 * PP * 256 * 4)      { KS_MAIN = 4; KS_OFF = 8; }
  else if (avail >= (size_t)2 * PP * 256 * 4) { KS_MAIN = 2; KS_OFF = 4; }
  else                                        { KS_MAIN = 1; KS_OFF = 2; }
  float* partial = (float*)(ws + off);
  int kst_m = 72 / KS_MAIN, kst_o = 72 / KS_OFF;

  hipMemsetAsync(zbuf, 0, 256, stream);
  bn_prep_k<<<1, 256, 0, stream>>>(bn2_g, bn2_b, bn2_m, bn2_v, convs_g, convs_b, convs_m, convs_v,
                                   emb_g, emb_b, emb_m, emb_v, bnscale, bnshift);
  auto pw = [&](const float* src, unsigned short* dst, int Ocnt, int KK, int NPAD) {
    int total = NPAD * KK * 256;
    prep_w_k<<<(total + 255) / 256, 256, 0, stream>>>(src, dst, Ocnt, KK, NPAD);
  };
  pw(off1_w, W2_off1, 18, 9, 128);
  pw(off2_w, W2_off2, 18, 9, 128);
  pw(dc1_w,  W2_dc1, 256, 9, 256);
  pw(dc2_w,  W2_dc2, 256, 9, 256);
  for (int i = 0; i < 4; ++i) pw(convs_w + (size_t)i * 2304 * 256, W2_c + (size_t)i * 2304 * 256, 256, 9, 256);
  pw(logit_w, W2_logit, 183, 1, 256);
  pw(emb_w,   W2_emb,   256, 1, 256);

  const dim3 blk(256);
  int order[5] = {1, 0, 2, 3, 4};
  for (int li = 0; li < 5; ++li) {
    int l = order[li];
    resize_k<<<PP, 256, 0, stream>>>(feats[l], Rb, fsz[l]);
    // off1
    mm_k<1><<<dim3(128, 1, KS_OFF), blk, 0, stream>>>(Rb, W2_off1, partial, zbuf, 2304, kst_o, 128);
    red_k<0><<<512, 256, 0, stream>>>(partial, KS_OFF, 128, 32, O, nullptr, off1_b, nullptr, nullptr);
    sample_k<<<dim3(2048, 9), blk, 0, stream>>>(Rb, O, S);
    // dc1
    mm_k<0><<<dim3(128, 2, KS_MAIN), blk, 0, stream>>>(S, W2_dc1, partial, zbuf, 2304, kst_m, 256);
    red_k<1><<<4096, 256, 0, stream>>>(partial, KS_MAIN, 256, 256, nullptr, H, nullptr, nullptr, nullptr);
    // off2
    mm_k<1><<<dim3(128, 1, KS_OFF), blk, 0, stream>>>(H, W2_off2, partial, zbuf, 2304, kst_o, 128);
    red_k<0><<<512, 256, 0, stream>>>(partial, KS_OFF, 128, 32, O, nullptr, off2_b, nullptr, nullptr);
    sample_k<<<dim3(2048, 9), blk, 0, stream>>>(H, O, S);
    // dc2 (+bn+relu, sum into X)
    mm_k<0><<<dim3(128, 2, KS_MAIN), blk, 0, stream>>>(S, W2_dc2, partial, zbuf, 2304, kst_m, 256);
    if (li == 0)
      red_k<4><<<4096, 256, 0, stream>>>(partial, KS_MAIN, 256, 256, X, nullptr, nullptr, bnscale, bnshift);
    else
      red_k<3><<<4096, 256, 0, stream>>>(partial, KS_MAIN, 256, 256, X, nullptr, nullptr, bnscale, bnshift);
  }
  f2b_k<<<4096, 256, 0, stream>>>(X, Xb);

  unsigned short* bufs[2] = {buf0, buf1};
  const unsigned short* cur = Xb;
  for (int i = 0; i < 4; ++i) {
    mm_k<1><<<dim3(128, 2, KS_MAIN), blk, 0, stream>>>(cur, W2_c + (size_t)i * 2304 * 256,
                                                       partial, zbuf, 2304, kst_m, 256);
    red_k<2><<<4096, 256, 0, stream>>>(partial, KS_MAIN, 256, 256, nullptr, bufs[i & 1],
                                       nullptr, bnscale + (1 + i) * 256, bnshift + (1 + i) * 256);
    cur = bufs[i & 1];
  }

  float* outp = (float*)d_out;
  mm_k<0><<<dim3(128, 2, 1), blk, 0, stream>>>(cur, W2_logit, partial, zbuf, 256, 8, 256);
  red_k<5><<<2944, 256, 0, stream>>>(partial, 1, 256, 184, outp, nullptr, logit_b, nullptr, nullptr);
  mm_k<0><<<dim3(128, 2, 1), blk, 0, stream>>>(cur, W2_emb, partial, zbuf, 256, 8, 256);
  red_k<6><<<4096, 256, 0, stream>>>(partial, 1, 256, 256, outp + (size_t)183 * PP, nullptr,
                                     nullptr, bnscale + 5 * 256, bnshift + 5 * 256);
}

// Round 3
// 1450.584 us; speedup vs baseline: 17.8254x; 1.0630x over previous
//
#include <hip/hip_runtime.h>
#include <stdint.h>

#define EPS_BN 1e-5f
constexpr int PP = 16384;   // 128*128 pixels at fusion resolution
using short8 = __attribute__((ext_vector_type(8))) short;
using f32x4  = __attribute__((ext_vector_type(4))) float;
typedef unsigned short u16;

__device__ inline float bf2f(u16 u) {
  unsigned v = ((unsigned)u) << 16; float f; __builtin_memcpy(&f, &v, 4); return f;
}
__device__ inline u16 f2bf(float f) {
  unsigned b; __builtin_memcpy(&b, &f, 4);
  b += 0x7FFFu + ((b >> 16) & 1u);
  return (u16)(b >> 16);
}

#define GLD16(g, l) __builtin_amdgcn_global_load_lds( \
    (__attribute__((address_space(1))) void*)(void*)(g), \
    (__attribute__((address_space(3))) void*)(void*)(l), 16, 0, 0)

// ---------------- BN param prep ----------------
__global__ void bn_prep_k(const float* __restrict__ g0, const float* __restrict__ b0,
                          const float* __restrict__ m0, const float* __restrict__ v0,
                          const float* __restrict__ cg, const float* __restrict__ cb,
                          const float* __restrict__ cm, const float* __restrict__ cv,
                          const float* __restrict__ eg, const float* __restrict__ eb,
                          const float* __restrict__ em, const float* __restrict__ ev,
                          float* __restrict__ scale, float* __restrict__ shift) {
  int c = threadIdx.x;
  float s = g0[c] * rsqrtf(v0[c] + EPS_BN);
  scale[c] = s; shift[c] = b0[c] - m0[c] * s;
#pragma unroll
  for (int i = 0; i < 4; ++i) {
    float si = cg[i*256+c] * rsqrtf(cv[i*256+c] + EPS_BN);
    scale[(1+i)*256+c] = si; shift[(1+i)*256+c] = cb[i*256+c] - cm[i*256+c]*si;
  }
  float se = eg[c] * rsqrtf(ev[c] + EPS_BN);
  scale[5*256+c] = se; shift[5*256+c] = eb[c] - em[c]*se;
}

// ---------------- weight prep: w[O][256][KK] fp32 -> W2[o][k*256+c] bf16, pad o>=Ocnt
__global__ void prep_w_k(const float* __restrict__ w, u16* __restrict__ W2,
                         int Ocnt, int KK, int NPAD) {
  int idx = blockIdx.x * 256 + threadIdx.x;
  int total = NPAD * KK * 256;
  if (idx >= total) return;
  int o = idx / (KK * 256); int rem = idx - o * (KK * 256);
  int kpt = rem >> 8, c = rem & 255;
  W2[idx] = (o < Ocnt) ? f2bf(w[(o * 256 + c) * KK + kpt]) : (u16)0;
}

// ---------------- NCHW fp32 -> NHWC bf16 transpose (coalesced both sides via LDS)
// grid (P/64, 4), block 256
__global__ void tr_k(const float* __restrict__ in, u16* __restrict__ out, int P) {
  __shared__ float tile[64][65];
  int p0 = blockIdx.x * 64, c0 = blockIdx.y * 64;
  int t = threadIdx.x;
  int tl = t & 63, tg = t >> 6;
#pragma unroll
  for (int i = 0; i < 16; ++i) {
    int c = tg * 16 + i;
    tile[c][tl] = in[(size_t)(c0 + c) * P + p0 + tl];
  }
  __syncthreads();
  int px = t >> 2, cq = t & 3;
#pragma unroll
  for (int pass = 0; pass < 2; ++pass) {
    int c = cq * 8 + pass * 32;
    u16 r[8];
#pragma unroll
    for (int j = 0; j < 8; ++j) r[j] = f2bf(tile[c + j][px]);
    *(short8*)(out + (size_t)(p0 + px) * 256 + c0 + c) = *(short8*)r;
  }
}

// ---------------- bilinear resize (align_corners) on NHWC bf16 -> 128x128 NHWC bf16
// grid (PP/8), block 256: 8 px/block, 32 lanes/px, 8 ch/lane
__global__ void rs_k(const u16* __restrict__ in, u16* __restrict__ out, int Hs) {
  int t = threadIdx.x;
  int p = blockIdx.x * 8 + (t >> 5), q = t & 31;
  int oy = p >> 7, ox = p & 127;
  float sc = (float)(Hs - 1) / 127.0f;
  float ys = oy * sc, xs = ox * sc;
  int y0 = (int)ys; if (y0 > Hs - 2) y0 = Hs - 2;
  int x0 = (int)xs; if (x0 > Hs - 2) x0 = Hs - 2;
  float wy = ys - (float)y0, wx = xs - (float)x0;
  const u16* b00 = in + ((size_t)(y0 * Hs + x0)) * 256 + q * 8;
  short8 v00 = *(const short8*)b00;
  short8 v01 = *(const short8*)(b00 + 256);
  short8 v10 = *(const short8*)(b00 + (size_t)Hs * 256);
  short8 v11 = *(const short8*)(b00 + (size_t)Hs * 256 + 256);
  u16 r[8];
#pragma unroll
  for (int j = 0; j < 8; ++j) {
    float a = bf2f((u16)v00[j]) * (1.f - wx) + bf2f((u16)v01[j]) * wx;
    float b = bf2f((u16)v10[j]) * (1.f - wx) + bf2f((u16)v11[j]) * wx;
    r[j] = f2bf(a * (1.f - wy) + b * wy);
  }
  *(short8*)(out + (size_t)p * 256 + q * 8) = *(short8*)r;
}

// ---------------- deform sampler (batched over levels)
// in: NHWC bf16 [MG rows as level<<14|pixel][256]; off fp32 [MG][32]; S bf16 [MG][2304]
__global__ void sample_k(const u16* __restrict__ in, const float* __restrict__ off,
                         u16* __restrict__ S) {
  int t = threadIdx.x;
  int k  = blockIdx.y;
  int gp = blockIdx.x * 8 + (t >> 5);
  int q  = t & 31;
  int lvl = gp >> 14, pl = gp & 16383;
  float2 o2 = *reinterpret_cast<const float2*>(off + (size_t)gp * 32 + 2 * k);
  int y = pl >> 7, x = pl & 127;
  float yy = (float)(y + k / 3 - 1) + o2.x;
  float xx = (float)(x + k % 3 - 1) + o2.y;
  float y0f = floorf(yy), x0f = floorf(xx);
  float wy = yy - y0f, wx = xx - x0f;
  int y0 = (int)y0f, x0 = (int)x0f;
  float w00 = (1.f-wy)*(1.f-wx), w01 = (1.f-wy)*wx, w10 = wy*(1.f-wx), w11 = wy*wx;
  float o[8] = {0,0,0,0,0,0,0,0};
  const u16* base = in + ((size_t)lvl << 14) * 256 + q * 8;
  auto corner = [&](int yi, int xi, float wgt) {
    if ((unsigned)yi < 128u && (unsigned)xi < 128u) {
      short8 v = *(const short8*)(base + (size_t)((yi << 7) + xi) * 256);
#pragma unroll
      for (int j = 0; j < 8; ++j) o[j] += wgt * bf2f((u16)v[j]);
    }
  };
  corner(y0, x0, w00); corner(y0, x0 + 1, w01);
  corner(y0 + 1, x0, w10); corner(y0 + 1, x0 + 1, w11);
  u16 r[8];
#pragma unroll
  for (int j = 0; j < 8; ++j) r[j] = f2bf(o[j]);
  *(short8*)(S + (size_t)gp * 2304 + k * 256 + q * 8) = *(short8*)r;
}

// ---------------- unified MFMA GEMM, epilogue fused, no split-K
// C[p,oc] = sum_k A[p,k] * B[oc,k]
// MODE 0: A dense bf16 [M][Ktot].  MODE 1: A NHWC bf16 [(lvl,128,128)][256], im2col 3x3 pad=1.
// Tile: BM=MW*AM*16 x BN=NW*AN*16, 4 waves (MW*NW=4), BK=32.
// EPI 1: fp32 [p][32] + bias(oc<18)   2: bf16 [p][256]   3: bn+relu bf16 [p][256]
// EPI 4: fp32 NCHW + bias (oc<OutN)   5: fp32 NCHW bn+relu
template<int MODE, int AM, int AN, int MW, int NW, int EPI>
__launch_bounds__(256)
__global__ void mm_k(const u16* __restrict__ A, const u16* __restrict__ B,
                     const u16* __restrict__ zbuf,
                     float* __restrict__ oF, u16* __restrict__ oB,
                     const float* __restrict__ bias,
                     const float* __restrict__ scale, const float* __restrict__ shift,
                     int Ktot, int ksteps, int OutN) {
  constexpr int BM = MW * AM * 16, BN = NW * AN * 16;
  __shared__ u16 sA[BM * 32];
  __shared__ u16 sB[BN * 32];
  char* sAb = (char*)sA; char* sBb = (char*)sB;
  const int t = threadIdx.x;
  const int w = t >> 6, l = t & 63;
  const int lr = l & 15, lq = l >> 4;
  const int wm = w / NW, wn = w % NW;
  int bx = blockIdx.x;
  { int n8 = gridDim.x >> 3; bx = (bx & 7) * n8 + (bx >> 3); }  // bijective (gridDim.x % 8 == 0)
  const int p0 = bx * BM, n0 = blockIdx.y * BN;

  f32x4 acc[AM][AN];
#pragma unroll
  for (int m = 0; m < AM; ++m)
#pragma unroll
    for (int n = 0; n < AN; ++n) acc[m][n] = (f32x4){0.f, 0.f, 0.f, 0.f};

  for (int ks = 0; ks < ksteps; ++ks) {
    int k0 = ks * 32;
    // ---- stage B [BN][32]
    if constexpr (BN * 4 >= 256) {
#pragma unroll
      for (int it = 0; it < BN * 4 / 256; ++it) {
        int ch = it * 256 + t;
        GLD16(B + (size_t)(n0 + (ch >> 2)) * Ktot + k0 + (ch & 3) * 8,
              sBb + it * 4096 + w * 1024);
      }
    } else {
      if (t < BN * 4)
        GLD16(B + (size_t)(n0 + (t >> 2)) * Ktot + k0 + (t & 3) * 8, sBb + w * 1024);
    }
    // ---- stage A [BM][32]
    if constexpr (MODE == 0) {
#pragma unroll
      for (int it = 0; it < BM * 4 / 256; ++it) {
        int ch = it * 256 + t;
        GLD16(A + (size_t)(p0 + (ch >> 2)) * Ktot + k0 + (ch & 3) * 8,
              sAb + it * 4096 + w * 1024);
      }
    } else {
      int kpt = k0 >> 8, c0 = k0 & 255;
      int dy = kpt / 3 - 1, dx = kpt % 3 - 1;
#pragma unroll
      for (int it = 0; it < BM * 4 / 256; ++it) {
        int ch = it * 256 + t;
        int gr = p0 + (ch >> 2);
        int lvl = gr >> 14, pl = gr & 16383;
        int yy = (pl >> 7) + dy, xx = (pl & 127) + dx;
        const u16* src = ((unsigned)yy < 128u && (unsigned)xx < 128u)
            ? A + ((size_t)(lvl << 14) + (yy << 7) + xx) * 256 + c0 + (ch & 3) * 8
            : zbuf;
        GLD16(src, sAb + it * 4096 + w * 1024);
      }
    }
    __syncthreads();
    short8 af[AM], bf[AN];
#pragma unroll
    for (int m = 0; m < AM; ++m)
      af[m] = *(const short8*)(sAb + (((wm * AM + m) * 16 + lr) << 6) + (lq << 4));
#pragma unroll
    for (int n = 0; n < AN; ++n)
      bf[n] = *(const short8*)(sBb + (((wn * AN + n) * 16 + lr) << 6) + (lq << 4));
#pragma unroll
    for (int m = 0; m < AM; ++m)
#pragma unroll
      for (int n = 0; n < AN; ++n)
        acc[m][n] = __builtin_amdgcn_mfma_f32_16x16x32_bf16(af[m], bf[n], acc[m][n], 0, 0, 0);
    __syncthreads();
  }

  // ---- fused epilogue
#pragma unroll
  for (int m = 0; m < AM; ++m) {
    int prow = p0 + (wm * AM + m) * 16 + lq * 4;
#pragma unroll
    for (int n = 0; n < AN; ++n) {
      int oc = n0 + (wn * AN + n) * 16 + lr;
      if constexpr (EPI == 1) {
        float bs = (oc < 18) ? bias[oc] : 0.f;
#pragma unroll
        for (int r = 0; r < 4; ++r) oF[(size_t)(prow + r) * 32 + oc] = acc[m][n][r] + bs;
      } else if constexpr (EPI == 2) {
#pragma unroll
        for (int r = 0; r < 4; ++r) oB[(size_t)(prow + r) * 256 + oc] = f2bf(acc[m][n][r]);
      } else if constexpr (EPI == 3) {
        float sc = scale[oc], sh = shift[oc];
#pragma unroll
        for (int r = 0; r < 4; ++r)
          oB[(size_t)(prow + r) * 256 + oc] = f2bf(fmaxf(acc[m][n][r] * sc + sh, 0.f));
      } else if constexpr (EPI == 4) {
        if (oc < OutN) {
          float bs = bias[oc];
          float4 v = {acc[m][n][0] + bs, acc[m][n][1] + bs, acc[m][n][2] + bs, acc[m][n][3] + bs};
          *(float4*)(oF + (size_t)oc * PP + prow) = v;
        }
      } else {  // EPI 5
        float sc = scale[oc], sh = shift[oc];
        float4 v = {fmaxf(acc[m][n][0] * sc + sh, 0.f), fmaxf(acc[m][n][1] * sc + sh, 0.f),
                    fmaxf(acc[m][n][2] * sc + sh, 0.f), fmaxf(acc[m][n][3] * sc + sh, 0.f)};
        *(float4*)(oF + (size_t)oc * PP + prow) = v;
      }
    }
  }
}

// ---------------- sum 5 branch outputs (bf16) in fp32 -> bf16
__global__ void sum5_k(const u16* __restrict__ H2, u16* __restrict__ out) {
  size_t base = ((size_t)blockIdx.x * 256 + threadIdx.x) * 8;
  float a[8] = {0,0,0,0,0,0,0,0};
#pragma unroll
  for (int lvl = 0; lvl < 5; ++lvl) {
    short8 v = *(const short8*)(H2 + (size_t)lvl * PP * 256 + base);
#pragma unroll
    for (int j = 0; j < 8; ++j) a[j] += bf2f((u16)v[j]);
  }
  u16 r[8];
#pragma unroll
  for (int j = 0; j < 8; ++j) r[j] = f2bf(a[j]);
  *(short8*)(out + base) = *(short8*)r;
}

extern "C" void kernel_launch(void* const* d_in, const int* in_sizes, int n_in,
                              void* d_out, int out_size, void* d_ws, size_t ws_size,
                              hipStream_t stream) {
  const float* feats[5];
  for (int i = 0; i < 5; ++i) feats[i] = (const float*)d_in[i];
  int fsz[5] = {256, 128, 64, 32, 16};
  const float* off1_w = (const float*)d_in[5];
  const float* off1_b = (const float*)d_in[6];
  const float* dc1_w  = (const float*)d_in[7];
  const float* off2_w = (const float*)d_in[8];
  const float* off2_b = (const float*)d_in[9];
  const float* dc2_w  = (const float*)d_in[10];
  const float* bn2_g  = (const float*)d_in[11];
  const float* bn2_b  = (const float*)d_in[12];
  const float* bn2_m  = (const float*)d_in[13];
  const float* bn2_v  = (const float*)d_in[14];
  const float* convs_w = (const float*)d_in[15];
  const float* convs_g = (const float*)d_in[16];
  const float* convs_b = (const float*)d_in[17];
  const float* convs_m = (const float*)d_in[18];
  const float* convs_v = (const float*)d_in[19];
  const float* emb_w  = (const float*)d_in[20];
  const float* emb_g  = (const float*)d_in[21];
  const float* emb_b  = (const float*)d_in[22];
  const float* emb_m  = (const float*)d_in[23];
  const float* emb_v  = (const float*)d_in[24];
  const float* logit_w = (const float*)d_in[25];
  const float* logit_b = (const float*)d_in[26];

  char* ws = (char*)d_ws;
  size_t off = 0;
  auto alloc = [&](size_t bytes) { char* p = ws + off; off += (bytes + 255) & ~255ull; return p; };
  float* bnscale = (float*)alloc(6 * 256 * 4);
  float* bnshift = (float*)alloc(6 * 256 * 4);
  u16* zbuf = (u16*)alloc(256);
  u16* W2_off1 = (u16*)alloc((size_t)32 * 2304 * 2);
  u16* W2_off2 = (u16*)alloc((size_t)32 * 2304 * 2);
  u16* W2_dc1  = (u16*)alloc((size_t)256 * 2304 * 2);
  u16* W2_dc2  = (u16*)alloc((size_t)256 * 2304 * 2);
  u16* W2_c    = (u16*)alloc((size_t)4 * 256 * 2304 * 2);
  u16* W2_logit = (u16*)alloc((size_t)256 * 256 * 2);
  u16* W2_emb   = (u16*)alloc((size_t)256 * 256 * 2);
  u16* R_all  = (u16*)alloc((size_t)5 * PP * 256 * 2);
  u16* H_all  = (u16*)alloc((size_t)5 * PP * 256 * 2);
  u16* H2_all = (u16*)alloc((size_t)5 * PP * 256 * 2);
  float* O    = (float*)alloc((size_t)5 * PP * 32 * 4);
  u16* Xb     = (u16*)alloc((size_t)PP * 256 * 2);
  // S gets the rest; Ftmp (transpose scratch, max 33.5 MB) aliases S.
  size_t avail = (ws_size > off) ? (ws_size - off) : 0;
  size_t sbytes = (size_t)PP * 2304 * 2;          // per-level im2col
  int G = (int)(avail / sbytes);
  if (G > 5) G = 5; if (G < 1) G = 1;
  u16* S = (u16*)(ws + off);
  u16* Ftmp = S;
  // conv-stack ping-pong buffers alias dead R_all slices
  u16* cb0 = R_all;
  u16* cb1 = R_all + (size_t)PP * 256;

  hipMemsetAsync(zbuf, 0, 256, stream);
  bn_prep_k<<<1, 256, 0, stream>>>(bn2_g, bn2_b, bn2_m, bn2_v, convs_g, convs_b, convs_m, convs_v,
                                   emb_g, emb_b, emb_m, emb_v, bnscale, bnshift);
  auto pw = [&](const float* src, u16* dst, int Ocnt, int KK, int NPAD) {
    int total = NPAD * KK * 256;
    prep_w_k<<<(total + 255) / 256, 256, 0, stream>>>(src, dst, Ocnt, KK, NPAD);
  };
  pw(off1_w, W2_off1, 18, 9, 32);
  pw(off2_w, W2_off2, 18, 9, 32);
  pw(dc1_w,  W2_dc1, 256, 9, 256);
  pw(dc2_w,  W2_dc2, 256, 9, 256);
  for (int i = 0; i < 4; ++i) pw(convs_w + (size_t)i * 2304 * 256, W2_c + (size_t)i * 2304 * 256, 256, 9, 256);
  pw(logit_w, W2_logit, 183, 1, 256);
  pw(emb_w,   W2_emb,   256, 1, 256);

  const dim3 blk(256);
  // ---- build R_all: NHWC bf16 at 128x128 per level
  for (int lvl = 0; lvl < 5; ++lvl) {
    int P = fsz[lvl] * fsz[lvl];
    u16* dst = (lvl == 1) ? (R_all + (size_t)PP * 256) : Ftmp;
    tr_k<<<dim3(P / 64, 4), blk, 0, stream>>>(feats[lvl], dst, P);
    if (lvl != 1)
      rs_k<<<dim3(PP / 8), blk, 0, stream>>>(Ftmp, R_all + (size_t)lvl * PP * 256, fsz[lvl]);
  }

  // ---- branch pipeline in level-groups of G
  int done = 0;
  while (done < 5) {
    int Gc = (5 - done < G) ? (5 - done) : G;
    int MG = Gc * PP;
    const u16* Rg = R_all + (size_t)done * PP * 256;
    u16* Hg = H_all + (size_t)done * PP * 256;
    u16* H2g = H2_all + (size_t)done * PP * 256;
    // off1 -> O
    mm_k<1, 4, 1, 2, 2, 1><<<dim3(MG / 128, 1), blk, 0, stream>>>(
        Rg, W2_off1, zbuf, O, nullptr, off1_b, nullptr, nullptr, 2304, 72, 32);
    sample_k<<<dim3(MG / 8, 9), blk, 0, stream>>>(Rg, O, S);
    // dc1 -> H (bf16)
    if (Gc >= 3)
      mm_k<0, 8, 4, 1, 4, 2><<<dim3(MG / 128, 1), blk, 0, stream>>>(
          S, W2_dc1, zbuf, nullptr, Hg, nullptr, nullptr, nullptr, 2304, 72, 256);
    else
      mm_k<0, 4, 4, 2, 2, 2><<<dim3(MG / 128, 2), blk, 0, stream>>>(
          S, W2_dc1, zbuf, nullptr, Hg, nullptr, nullptr, nullptr, 2304, 72, 256);
    // off2 -> O
    mm_k<1, 4, 1, 2, 2, 1><<<dim3(MG / 128, 1), blk, 0, stream>>>(
        Hg, W2_off2, zbuf, O, nullptr, off2_b, nullptr, nullptr, 2304, 72, 32);
    sample_k<<<dim3(MG / 8, 9), blk, 0, stream>>>(Hg, O, S);
    // dc2 -> H2 (bn2+relu, bf16)
    if (Gc >= 3)
      mm_k<0, 8, 4, 1, 4, 3><<<dim3(MG / 128, 1), blk, 0, stream>>>(
          S, W2_dc2, zbuf, nullptr, H2g, nullptr, bnscale, bnshift, 2304, 72, 256);
    else
      mm_k<0, 4, 4, 2, 2, 3><<<dim3(MG / 128, 2), blk, 0, stream>>>(
          S, W2_dc2, zbuf, nullptr, H2g, nullptr, bnscale, bnshift, 2304, 72, 256);
    done += Gc;
  }

  // ---- sum branches
  sum5_k<<<dim3(2048), blk, 0, stream>>>(H2_all, Xb);

  // ---- conv stack (64x64 tiles, grid 1024)
  const u16* cur = Xb;
  u16* cbuf[2] = {cb0, cb1};
  for (int i = 0; i < 4; ++i) {
    mm_k<1, 2, 2, 2, 2, 3><<<dim3(PP / 64, 4), blk, 0, stream>>>(
        cur, W2_c + (size_t)i * 2304 * 256, zbuf, nullptr, cbuf[i & 1],
        nullptr, bnscale + (1 + i) * 256, bnshift + (1 + i) * 256, 2304, 72, 256);
    cur = cbuf[i & 1];
  }

  // ---- heads
  float* outp = (float*)d_out;
  mm_k<0, 2, 2, 2, 2, 4><<<dim3(PP / 64, 4), blk, 0, stream>>>(
      cur, W2_logit, zbuf, outp, nullptr, logit_b, nullptr, nullptr, 256, 8, 183);
  mm_k<0, 2, 2, 2, 2, 5><<<dim3(PP / 64, 4), blk, 0, stream>>>(
      cur, W2_emb, zbuf, outp + (size_t)183 * PP, nullptr, nullptr,
      bnscale + 5 * 256, bnshift + 5 * 256, 256, 8, 256);
}

// Round 4
// 995.098 us; speedup vs baseline: 25.9847x; 1.4577x over previous
//
#include <hip/hip_runtime.h>
#include <stdint.h>

#define EPS_BN 1e-5f
constexpr int PP = 16384;   // 128*128 pixels at fusion resolution
using short8 = __attribute__((ext_vector_type(8))) short;
using f32x4  = __attribute__((ext_vector_type(4))) float;
typedef unsigned short u16;

__device__ inline float bf2f(u16 u) {
  unsigned v = ((unsigned)u) << 16; float f; __builtin_memcpy(&f, &v, 4); return f;
}
__device__ inline u16 f2bf(float f) {
  unsigned b; __builtin_memcpy(&b, &f, 4);
  b += 0x7FFFu + ((b >> 16) & 1u);
  return (u16)(b >> 16);
}

#define GLD16(g, l) __builtin_amdgcn_global_load_lds( \
    (__attribute__((address_space(1))) void*)(void*)(g), \
    (__attribute__((address_space(3))) void*)(void*)(l), 16, 0, 0)

// ---------------- BN param prep ----------------
__global__ void bn_prep_k(const float* __restrict__ g0, const float* __restrict__ b0,
                          const float* __restrict__ m0, const float* __restrict__ v0,
                          const float* __restrict__ cg, const float* __restrict__ cb,
                          const float* __restrict__ cm, const float* __restrict__ cv,
                          const float* __restrict__ eg, const float* __restrict__ eb,
                          const float* __restrict__ em, const float* __restrict__ ev,
                          float* __restrict__ scale, float* __restrict__ shift) {
  int c = threadIdx.x;
  float s = g0[c] * rsqrtf(v0[c] + EPS_BN);
  scale[c] = s; shift[c] = b0[c] - m0[c] * s;
#pragma unroll
  for (int i = 0; i < 4; ++i) {
    float si = cg[i*256+c] * rsqrtf(cv[i*256+c] + EPS_BN);
    scale[(1+i)*256+c] = si; shift[(1+i)*256+c] = cb[i*256+c] - cm[i*256+c]*si;
  }
  float se = eg[c] * rsqrtf(ev[c] + EPS_BN);
  scale[5*256+c] = se; shift[5*256+c] = eb[c] - em[c]*se;
}

// ---------------- weight prep: w[O][256][KK] fp32 -> W2[o][k*256+c] bf16, pad o>=Ocnt
__global__ void prep_w_k(const float* __restrict__ w, u16* __restrict__ W2,
                         int Ocnt, int KK, int NPAD) {
  int idx = blockIdx.x * 256 + threadIdx.x;
  int total = NPAD * KK * 256;
  if (idx >= total) return;
  int o = idx / (KK * 256); int rem = idx - o * (KK * 256);
  int kpt = rem >> 8, c = rem & 255;
  W2[idx] = (o < Ocnt) ? f2bf(w[(o * 256 + c) * KK + kpt]) : (u16)0;
}

// ---------------- NCHW fp32 -> NHWC bf16 transpose
__global__ void tr_k(const float* __restrict__ in, u16* __restrict__ out, int P) {
  __shared__ float tile[64][65];
  int p0 = blockIdx.x * 64, c0 = blockIdx.y * 64;
  int t = threadIdx.x;
  int tl = t & 63, tg = t >> 6;
#pragma unroll
  for (int i = 0; i < 16; ++i) {
    int c = tg * 16 + i;
    tile[c][tl] = in[(size_t)(c0 + c) * P + p0 + tl];
  }
  __syncthreads();
  int px = t >> 2, cq = t & 3;
#pragma unroll
  for (int pass = 0; pass < 2; ++pass) {
    int c = cq * 8 + pass * 32;
    u16 r[8];
#pragma unroll
    for (int j = 0; j < 8; ++j) r[j] = f2bf(tile[c + j][px]);
    *(short8*)(out + (size_t)(p0 + px) * 256 + c0 + c) = *(short8*)r;
  }
}

// ---------------- bilinear resize (align_corners) NHWC bf16 -> 128x128 NHWC bf16
__global__ void rs_k(const u16* __restrict__ in, u16* __restrict__ out, int Hs) {
  int t = threadIdx.x;
  int p = blockIdx.x * 8 + (t >> 5), q = t & 31;
  int oy = p >> 7, ox = p & 127;
  float sc = (float)(Hs - 1) / 127.0f;
  float ys = oy * sc, xs = ox * sc;
  int y0 = (int)ys; if (y0 > Hs - 2) y0 = Hs - 2;
  int x0 = (int)xs; if (x0 > Hs - 2) x0 = Hs - 2;
  float wy = ys - (float)y0, wx = xs - (float)x0;
  const u16* b00 = in + ((size_t)(y0 * Hs + x0)) * 256 + q * 8;
  short8 v00 = *(const short8*)b00;
  short8 v01 = *(const short8*)(b00 + 256);
  short8 v10 = *(const short8*)(b00 + (size_t)Hs * 256);
  short8 v11 = *(const short8*)(b00 + (size_t)Hs * 256 + 256);
  u16 r[8];
#pragma unroll
  for (int j = 0; j < 8; ++j) {
    float a = bf2f((u16)v00[j]) * (1.f - wx) + bf2f((u16)v01[j]) * wx;
    float b = bf2f((u16)v10[j]) * (1.f - wx) + bf2f((u16)v11[j]) * wx;
    r[j] = f2bf(a * (1.f - wy) + b * wy);
  }
  *(short8*)(out + (size_t)p * 256 + q * 8) = *(short8*)r;
}

// ---------------- unified MFMA GEMM, BK=64, XOR-swizzled LDS, fused epilogue
// C[p,oc] = sum_k A[p,k] * B[oc,k];  B: [NStot rows=oc][Ktot] bf16
// MODE 0: A dense bf16 [M][Ktot]
// MODE 1: A NHWC bf16 [(lvl,128,128)][256], im2col 3x3 pad=1 (k = kpt*256+c)
// MODE 2: A NHWC feature + offs fp32 [gp][32]: deform-conv bilinear sampling fused
// EPI 1: fp32 [p][32] + bias(oc<18)   2: bf16 [p][256]   3: bn+relu bf16 [p][256]
// EPI 4: fp32 NCHW + bias (oc<OutN)   5: fp32 NCHW bn+relu
template<int MODE, int AM, int AN, int MW, int NW, int EPI>
__launch_bounds__(MW*NW*64)
__global__ void mm_k(const u16* __restrict__ A, const u16* __restrict__ B,
                     const float* __restrict__ offs, const u16* __restrict__ zbuf,
                     float* __restrict__ oF, u16* __restrict__ oB,
                     const float* __restrict__ bias,
                     const float* __restrict__ scale, const float* __restrict__ shift,
                     int Ktot, int ksteps, int OutN) {
  constexpr int BM = MW * AM * 16, BN = NW * AN * 16, NT = MW * NW * 64;
  constexpr int AITS = BM * 8 / NT, BITS = BN * 8 / NT;
  __shared__ u16 sA[BM * 64];   // [BM][128B], col-swizzled
  __shared__ u16 sB[BN * 64];
  char* sAb = (char*)sA; char* sBb = (char*)sB;
  const int t = threadIdx.x;
  const int w = t >> 6, l = t & 63;
  const int lr = l & 15, lq = l >> 4;
  const int wm = w / NW, wn = w % NW;
  int bx = blockIdx.x;
  { int n8 = gridDim.x >> 3; bx = (bx & 7) * n8 + (bx >> 3); }  // gridDim.x % 8 == 0
  const int p0 = bx * BM, n0 = blockIdx.y * BN;

  f32x4 acc[AM][AN];
#pragma unroll
  for (int m = 0; m < AM; ++m)
#pragma unroll
    for (int n = 0; n < AN; ++n) acc[m][n] = (f32x4){0.f, 0.f, 0.f, 0.f};

  // MODE 2 per-kpt caches (fixed rows per thread across K-steps)
  float cw0[AITS ? AITS : 1], cw1[AITS ? AITS : 1], cw2[AITS ? AITS : 1], cw3[AITS ? AITS : 1];
  int   cb0[AITS ? AITS : 1], cb1[AITS ? AITS : 1], cb2[AITS ? AITS : 1], cb3[AITS ? AITS : 1];

  for (int ks = 0; ks < ksteps; ++ks) {
    int k0 = ks * 64;
    // ---- stage B
#pragma unroll
    for (int it = 0; it < BITS; ++it) {
      int ch = it * NT + t;
      int row = ch >> 3, cl = (ch & 7) ^ (row & 7);
      GLD16(B + (size_t)(n0 + row) * Ktot + k0 + cl * 8, sBb + it * (NT * 16) + w * 1024);
    }
    // ---- stage A
    if constexpr (MODE == 0) {
#pragma unroll
      for (int it = 0; it < AITS; ++it) {
        int ch = it * NT + t;
        int row = ch >> 3, cl = (ch & 7) ^ (row & 7);
        GLD16(A + (size_t)(p0 + row) * Ktot + k0 + cl * 8, sAb + it * (NT * 16) + w * 1024);
      }
    } else if constexpr (MODE == 1) {
      int kpt = k0 >> 8, c0 = k0 & 255;
      int dy = kpt / 3 - 1, dx = kpt % 3 - 1;
#pragma unroll
      for (int it = 0; it < AITS; ++it) {
        int ch = it * NT + t;
        int row = ch >> 3, cl = (ch & 7) ^ (row & 7);
        int gp = p0 + row; int lvl = gp >> 14, pl = gp & 16383;
        int yy = (pl >> 7) + dy, xx = (pl & 127) + dx;
        const u16* src = ((unsigned)yy < 128u && (unsigned)xx < 128u)
            ? A + ((size_t)(lvl << 14) + (yy << 7) + xx) * 256 + c0 + cl * 8
            : zbuf;
        GLD16(src, sAb + it * (NT * 16) + w * 1024);
      }
    } else {  // MODE 2: fused deform sampling, reg -> swizzled ds_write
      if ((ks & 3) == 0) {
        int kpt = ks >> 2;
#pragma unroll
        for (int it = 0; it < AITS; ++it) {
          int row = (it * NT + t) >> 3;
          int gp = p0 + row; int lvl = gp >> 14, pl = gp & 16383;
          float2 o2 = *(const float2*)(offs + (size_t)gp * 32 + 2 * kpt);
          float yy = (float)((pl >> 7) + kpt / 3 - 1) + o2.x;
          float xx = (float)((pl & 127) + kpt % 3 - 1) + o2.y;
          float yf = floorf(yy), xf = floorf(xx);
          float wy = yy - yf, wx = xx - xf;
          int y0 = (int)yf, x0 = (int)xf;
          int lb = lvl << 14;
          bool v0 = ((unsigned)y0 < 128u), v1 = ((unsigned)(y0 + 1) < 128u);
          bool h0 = ((unsigned)x0 < 128u), h1 = ((unsigned)(x0 + 1) < 128u);
          cw0[it] = (1.f - wy) * (1.f - wx); cb0[it] = (v0 && h0) ? (lb + (y0 << 7) + x0) : -1;
          cw1[it] = (1.f - wy) * wx;         cb1[it] = (v0 && h1) ? (lb + (y0 << 7) + x0 + 1) : -1;
          cw2[it] = wy * (1.f - wx);         cb2[it] = (v1 && h0) ? (lb + ((y0 + 1) << 7) + x0) : -1;
          cw3[it] = wy * wx;                 cb3[it] = (v1 && h1) ? (lb + ((y0 + 1) << 7) + x0 + 1) : -1;
        }
      }
#pragma unroll
      for (int it = 0; it < AITS; ++it) {
        int ch = it * NT + t;
        int row = ch >> 3, cp = ch & 7, cl = cp ^ (row & 7);
        int cc = (k0 & 255) + cl * 8;
        float o[8] = {0,0,0,0,0,0,0,0};
        if (cb0[it] >= 0) { short8 v = *(const short8*)(A + (size_t)cb0[it] * 256 + cc);
#pragma unroll
          for (int j = 0; j < 8; ++j) o[j] += cw0[it] * bf2f((u16)v[j]); }
        if (cb1[it] >= 0) { short8 v = *(const short8*)(A + (size_t)cb1[it] * 256 + cc);
#pragma unroll
          for (int j = 0; j < 8; ++j) o[j] += cw1[it] * bf2f((u16)v[j]); }
        if (cb2[it] >= 0) { short8 v = *(const short8*)(A + (size_t)cb2[it] * 256 + cc);
#pragma unroll
          for (int j = 0; j < 8; ++j) o[j] += cw2[it] * bf2f((u16)v[j]); }
        if (cb3[it] >= 0) { short8 v = *(const short8*)(A + (size_t)cb3[it] * 256 + cc);
#pragma unroll
          for (int j = 0; j < 8; ++j) o[j] += cw3[it] * bf2f((u16)v[j]); }
        u16 r[8];
#pragma unroll
        for (int j = 0; j < 8; ++j) r[j] = f2bf(o[j]);
        *(short8*)(sAb + row * 128 + cp * 16) = *(short8*)r;
      }
    }
    __syncthreads();
    // ---- fragments + MFMA (two k-halves of the 64-wide step)
    short8 af[AM], bfr[AN];
#pragma unroll
    for (int h = 0; h < 2; ++h) {
#pragma unroll
      for (int m = 0; m < AM; ++m) {
        int ar = wm * AM * 16 + m * 16 + lr;
        af[m] = *(const short8*)(sAb + ar * 128 + (((h * 4 + lq) ^ (ar & 7)) << 4));
      }
#pragma unroll
      for (int n = 0; n < AN; ++n) {
        int br = wn * AN * 16 + n * 16 + lr;
        bfr[n] = *(const short8*)(sBb + br * 128 + (((h * 4 + lq) ^ (br & 7)) << 4));
      }
#pragma unroll
      for (int m = 0; m < AM; ++m)
#pragma unroll
        for (int n = 0; n < AN; ++n)
          acc[m][n] = __builtin_amdgcn_mfma_f32_16x16x32_bf16(af[m], bfr[n], acc[m][n], 0, 0, 0);
    }
    __syncthreads();
  }

  // ---- fused epilogue
#pragma unroll
  for (int m = 0; m < AM; ++m) {
    int prow = p0 + wm * AM * 16 + m * 16 + lq * 4;
#pragma unroll
    for (int n = 0; n < AN; ++n) {
      int oc = n0 + wn * AN * 16 + n * 16 + lr;
      if constexpr (EPI == 1) {
        float bs = (oc < 18) ? bias[oc] : 0.f;
#pragma unroll
        for (int r = 0; r < 4; ++r) oF[(size_t)(prow + r) * 32 + oc] = acc[m][n][r] + bs;
      } else if constexpr (EPI == 2) {
#pragma unroll
        for (int r = 0; r < 4; ++r) oB[(size_t)(prow + r) * 256 + oc] = f2bf(acc[m][n][r]);
      } else if constexpr (EPI == 3) {
        float sc = scale[oc], sh = shift[oc];
#pragma unroll
        for (int r = 0; r < 4; ++r)
          oB[(size_t)(prow + r) * 256 + oc] = f2bf(fmaxf(acc[m][n][r] * sc + sh, 0.f));
      } else if constexpr (EPI == 4) {
        if (oc < OutN) {
          float bs = bias[oc];
          float4 v = {acc[m][n][0] + bs, acc[m][n][1] + bs, acc[m][n][2] + bs, acc[m][n][3] + bs};
          *(float4*)(oF + (size_t)oc * PP + prow) = v;
        }
      } else {  // EPI 5
        float sc = scale[oc], sh = shift[oc];
        float4 v = {fmaxf(acc[m][n][0] * sc + sh, 0.f), fmaxf(acc[m][n][1] * sc + sh, 0.f),
                    fmaxf(acc[m][n][2] * sc + sh, 0.f), fmaxf(acc[m][n][3] * sc + sh, 0.f)};
        *(float4*)(oF + (size_t)oc * PP + prow) = v;
      }
    }
  }
}

// ---------------- sum 5 branch outputs (bf16) in fp32 -> bf16
__global__ void sum5_k(const u16* __restrict__ H2, u16* __restrict__ out) {
  size_t base = ((size_t)blockIdx.x * 256 + threadIdx.x) * 8;
  float a[8] = {0,0,0,0,0,0,0,0};
#pragma unroll
  for (int lvl = 0; lvl < 5; ++lvl) {
    short8 v = *(const short8*)(H2 + (size_t)lvl * PP * 256 + base);
#pragma unroll
    for (int j = 0; j < 8; ++j) a[j] += bf2f((u16)v[j]);
  }
  u16 r[8];
#pragma unroll
  for (int j = 0; j < 8; ++j) r[j] = f2bf(a[j]);
  *(short8*)(out + base) = *(short8*)r;
}

extern "C" void kernel_launch(void* const* d_in, const int* in_sizes, int n_in,
                              void* d_out, int out_size, void* d_ws, size_t ws_size,
                              hipStream_t stream) {
  const float* feats[5];
  for (int i = 0; i < 5; ++i) feats[i] = (const float*)d_in[i];
  int fsz[5] = {256, 128, 64, 32, 16};
  const float* off1_w = (const float*)d_in[5];
  const float* off1_b = (const float*)d_in[6];
  const float* dc1_w  = (const float*)d_in[7];
  const float* off2_w = (const float*)d_in[8];
  const float* off2_b = (const float*)d_in[9];
  const float* dc2_w  = (const float*)d_in[10];
  const float* bn2_g  = (const float*)d_in[11];
  const float* bn2_b  = (const float*)d_in[12];
  const float* bn2_m  = (const float*)d_in[13];
  const float* bn2_v  = (const float*)d_in[14];
  const float* convs_w = (const float*)d_in[15];
  const float* convs_g = (const float*)d_in[16];
  const float* convs_b = (const float*)d_in[17];
  const float* convs_m = (const float*)d_in[18];
  const float* convs_v = (const float*)d_in[19];
  const float* emb_w  = (const float*)d_in[20];
  const float* emb_g  = (const float*)d_in[21];
  const float* emb_b  = (const float*)d_in[22];
  const float* emb_m  = (const float*)d_in[23];
  const float* emb_v  = (const float*)d_in[24];
  const float* logit_w = (const float*)d_in[25];
  const float* logit_b = (const float*)d_in[26];

  char* ws = (char*)d_ws;
  size_t off = 0;
  auto alloc = [&](size_t bytes) { char* p = ws + off; off += (bytes + 255) & ~255ull; return p; };
  float* bnscale = (float*)alloc(6 * 256 * 4);
  float* bnshift = (float*)alloc(6 * 256 * 4);
  u16* zbuf = (u16*)alloc(256);
  u16* W2_off1 = (u16*)alloc((size_t)32 * 2304 * 2);
  u16* W2_off2 = (u16*)alloc((size_t)32 * 2304 * 2);
  u16* W2_dc1  = (u16*)alloc((size_t)256 * 2304 * 2);
  u16* W2_dc2  = (u16*)alloc((size_t)256 * 2304 * 2);
  u16* W2_c    = (u16*)alloc((size_t)4 * 256 * 2304 * 2);
  u16* W2_logit = (u16*)alloc((size_t)256 * 256 * 2);
  u16* W2_emb   = (u16*)alloc((size_t)256 * 256 * 2);
  u16* R_all  = (u16*)alloc((size_t)5 * PP * 256 * 2);
  u16* H_all  = (u16*)alloc((size_t)5 * PP * 256 * 2);
  u16* H2_all = (u16*)alloc((size_t)5 * PP * 256 * 2);
  float* O    = (float*)alloc((size_t)5 * PP * 32 * 4);
  u16* Xb     = (u16*)alloc((size_t)PP * 256 * 2);
  u16* Ftmp = H_all;                      // transpose scratch (used only pre-dc1)
  u16* cb0 = R_all;                       // conv-stack ping-pong (R dead by then)
  u16* cb1 = R_all + (size_t)PP * 256;

  hipMemsetAsync(zbuf, 0, 256, stream);
  bn_prep_k<<<1, 256, 0, stream>>>(bn2_g, bn2_b, bn2_m, bn2_v, convs_g, convs_b, convs_m, convs_v,
                                   emb_g, emb_b, emb_m, emb_v, bnscale, bnshift);
  auto pw = [&](const float* src, u16* dst, int Ocnt, int KK, int NPAD) {
    int total = NPAD * KK * 256;
    prep_w_k<<<(total + 255) / 256, 256, 0, stream>>>(src, dst, Ocnt, KK, NPAD);
  };
  pw(off1_w, W2_off1, 18, 9, 32);
  pw(off2_w, W2_off2, 18, 9, 32);
  pw(dc1_w,  W2_dc1, 256, 9, 256);
  pw(dc2_w,  W2_dc2, 256, 9, 256);
  for (int i = 0; i < 4; ++i) pw(convs_w + (size_t)i * 2304 * 256, W2_c + (size_t)i * 2304 * 256, 256, 9, 256);
  pw(logit_w, W2_logit, 183, 1, 256);
  pw(emb_w,   W2_emb,   256, 1, 256);

  const dim3 blk(256), blk512(512);
  // ---- build R_all: NHWC bf16 at 128x128 per level
  for (int lvl = 0; lvl < 5; ++lvl) {
    int P = fsz[lvl] * fsz[lvl];
    u16* dst = (lvl == 1) ? (R_all + (size_t)PP * 256) : Ftmp;
    tr_k<<<dim3(P / 64, 4), blk, 0, stream>>>(feats[lvl], dst, P);
    if (lvl != 1)
      rs_k<<<dim3(PP / 8), blk, 0, stream>>>(Ftmp, R_all + (size_t)lvl * PP * 256, fsz[lvl]);
  }

  constexpr int MG = 5 * PP;  // 81920 rows batched
  // off1 (batched): im2col conv -> O fp32 [gp][32]
  mm_k<1, 2, 2, 4, 1, 1><<<dim3(MG / 128, 1), blk, 0, stream>>>(
      R_all, W2_off1, nullptr, zbuf, O, nullptr, off1_b, nullptr, nullptr, 2304, 36, 32);
  // dc1 (batched, fused deform) -> H_all bf16
  mm_k<2, 4, 4, 2, 4, 2><<<dim3(MG / 128, 1), blk512, 0, stream>>>(
      R_all, W2_dc1, O, zbuf, nullptr, H_all, nullptr, nullptr, nullptr, 2304, 36, 256);
  // off2 (batched)
  mm_k<1, 2, 2, 4, 1, 1><<<dim3(MG / 128, 1), blk, 0, stream>>>(
      H_all, W2_off2, nullptr, zbuf, O, nullptr, off2_b, nullptr, nullptr, 2304, 36, 32);
  // dc2 (batched, fused deform, bn+relu) -> H2_all bf16
  mm_k<2, 4, 4, 2, 4, 3><<<dim3(MG / 128, 1), blk512, 0, stream>>>(
      H_all, W2_dc2, O, zbuf, nullptr, H2_all, nullptr, bnscale, bnshift, 2304, 36, 256);

  // ---- sum branches
  sum5_k<<<dim3(2048), blk, 0, stream>>>(H2_all, Xb);

  // ---- conv stack (64x128 tiles, grid 512)
  const u16* cur = Xb;
  u16* cbuf[2] = {cb0, cb1};
  for (int i = 0; i < 4; ++i) {
    mm_k<1, 2, 4, 2, 2, 3><<<dim3(PP / 64, 2), blk, 0, stream>>>(
        cur, W2_c + (size_t)i * 2304 * 256, nullptr, zbuf, nullptr, cbuf[i & 1],
        nullptr, bnscale + (1 + i) * 256, bnshift + (1 + i) * 256, 2304, 36, 256);
    cur = cbuf[i & 1];
  }

  // ---- heads (1x1, K=256)
  float* outp = (float*)d_out;
  mm_k<0, 2, 4, 2, 2, 4><<<dim3(PP / 64, 2), blk, 0, stream>>>(
      cur, W2_logit, nullptr, zbuf, outp, nullptr, logit_b, nullptr, nullptr, 256, 4, 183);
  mm_k<0, 2, 4, 2, 2, 5><<<dim3(PP / 64, 2), blk, 0, stream>>>(
      cur, W2_emb, nullptr, zbuf, outp + (size_t)183 * PP, nullptr, nullptr,
      bnscale + 5 * 256, bnshift + 5 * 256, 256, 4, 256);
}